// Round 2
// baseline (609.306 us; speedup 1.0000x reference)
//
#include <hip/hip_runtime.h>

// Problem constants (from reference)
#define Bdim   4
#define Tdim   1024
#define NLAB   64
#define Cdim   256
#define Ddim   512
#define HALF   256        // VALUE_DIM/2
#define BT     (Bdim*Tdim)
#define NBLK   256        // main-kernel grid size (64 labels x 4 d-chunks)

// Grid: 64 labels x 4 d-chunks (64 d's each) = 256 blocks, 512 threads (8 waves).
//
// KEY CHANGE vs 604.9us baseline: NO global atomics. The baseline ended with
// 262,144 device-scope atomicAdds onto the same 4KB (64 cache lines) from all
// 8 XCDs -> serialized cross-XCD RMWs ~ hundreds of us (the measured time).
// Now each block stores its 4x256 partial to a private d_ws slice (coalesced,
// contention-free) and a second kernel reduces 256 partials -> out.
//
// Retained latency levers (round-0): 8 waves -> 2 waves/SIMD; W tile register-
// prefetched at kernel start (HBM latency overlaps compaction + stage 1);
// 32 gather slots -> ~2 trips of the dependent gather chain per slot.
template <bool USE_WS>
__global__ __launch_bounds__(512) void vb_kernel(
    const int*   __restrict__ indices,   // [B*T]
    const float* __restrict__ scores,    // [B*T]
    const float* __restrict__ W,         // [NLAB, Ddim, Cdim]
    const int*   __restrict__ label,     // [B*T]
    const int*   __restrict__ index_p,   // [1]
    const float* __restrict__ weight,    // [VALUE_SIZE, Ddim]
    float*       __restrict__ dst)       // USE_WS ? ws[NBLK][Bdim*Cdim] : out[B,Cdim]
{
    const int l     = blockIdx.x & 63;
    const int chunk = blockIdx.x >> 6;       // 0..3 -> d in [chunk*64, chunk*64+64)
    const int tid   = threadIdx.x;
    const int lane  = tid & 63;
    const int wave  = tid >> 6;              // 0..7
    const int half  = (index_p[0] == 1) ? HALF : 0;
    const int dglob = half + chunk * 64;     // global d offset for this block

    __shared__ int   s_list[BT];             // 16 KB: matching flat bt indices
    __shared__ int   s_count;
    __shared__ float A_red[Bdim][64];        // 1 KB
    __shared__ float pool[8192];             // 32 KB, overlaid buffers:
    float (*A_part)[Bdim][64]  = (float (*)[Bdim][64])pool;   // [32][4][64] stage 1
    float (*P)[Bdim][Cdim]     = (float (*)[Bdim][Cdim])pool; // [8][4][256] stage 2

    if (tid == 0) s_count = 0;
    __syncthreads();

    // ---- W register prefetch (independent of everything below; overlaps
    //      its HBM latency with compaction + stage 1) ----
    const int c4 = lane * 4;                 // 4 consecutive c per thread
    float4 w_pre[8];
    #pragma unroll
    for (int dd = 0; dd < 8; ++dd) {
        int dloc = dd * 8 + wave;            // 0..63, wave-uniform
        w_pre[dd] = *(const float4*)(
            W + ((size_t)(l * Ddim + dglob + dloc) * Cdim + c4));
    }

    // ---- compact (b,t) with label == l : wave-aggregated (ballot) push ----
    #pragma unroll
    for (int i = 0; i < 2; ++i) {
        int4 lv = ((const int4*)label)[i * 512 + tid];   // bt = (i*512+tid)*4 + j
        int bt0 = (i * 512 + tid) * 4;
        int lv_arr[4] = {lv.x, lv.y, lv.z, lv.w};
        #pragma unroll
        for (int j = 0; j < 4; ++j) {
            bool m = (lv_arr[j] == l);
            unsigned long long mask = __ballot(m);
            int base_s = 0;
            if (lane == 0 && mask)
                base_s = atomicAdd(&s_count, __popcll(mask));
            base_s = __shfl(base_s, 0, 64);
            if (m) {
                int pre = __popcll(mask & ((1ull << lane) - 1ull));
                s_list[base_s + pre] = bt0 + j;
            }
        }
    }
    __syncthreads();
    const int count = s_count;   // no early-out: zero partial must be written

    // ---- stage 1: A[b,d] = sum over matches of score * weight[idx, dglob+d] ----
    // 32 slots = wave(8) x q(4); each slot's 16 lanes load one match row as float4.
    const int q    = lane >> 4;              // 0..3
    const int cl   = lane & 15;              // 0..15 -> d = cl*4..cl*4+3
    const int slot = wave * 4 + q;           // 0..31

    float4 acc0 = {0,0,0,0}, acc1 = {0,0,0,0}, acc2 = {0,0,0,0}, acc3 = {0,0,0,0};
    for (int m = slot; m < count; m += 32) {
        int   bt  = s_list[m];
        int   b   = bt >> 10;                // T = 1024
        float s   = scores[bt];
        int   idx = indices[bt];
        const float4 w = *(const float4*)(weight + (size_t)idx * Ddim + dglob + cl * 4);
        float s0 = (b == 0) ? s : 0.0f;
        float s1 = (b == 1) ? s : 0.0f;
        float s2 = (b == 2) ? s : 0.0f;
        float s3 = (b == 3) ? s : 0.0f;
        acc0.x += s0 * w.x; acc0.y += s0 * w.y; acc0.z += s0 * w.z; acc0.w += s0 * w.w;
        acc1.x += s1 * w.x; acc1.y += s1 * w.y; acc1.z += s1 * w.z; acc1.w += s1 * w.w;
        acc2.x += s2 * w.x; acc2.y += s2 * w.y; acc2.z += s2 * w.z; acc2.w += s2 * w.w;
        acc3.x += s3 * w.x; acc3.y += s3 * w.y; acc3.z += s3 * w.z; acc3.w += s3 * w.w;
    }
    *(float4*)&A_part[slot][0][cl * 4] = acc0;
    *(float4*)&A_part[slot][1][cl * 4] = acc1;
    *(float4*)&A_part[slot][2][cl * 4] = acc2;
    *(float4*)&A_part[slot][3][cl * 4] = acc3;
    __syncthreads();

    // reduce 32 slots: threads = b(4) x d(64), first 256 threads
    if (tid < 256) {
        int b = tid >> 6, d = tid & 63;
        float s = 0.0f;
        #pragma unroll
        for (int k = 0; k < 32; ++k) s += A_part[k][b][d];
        A_red[b][d] = s;
    }
    __syncthreads();   // also retires all A_part reads before pool is reused as P

    // ---- stage 2: P[b,c] = sum_d A[b,d] * W[l, dglob+d, c] (W from regs) ----
    float4 acc[Bdim];
    #pragma unroll
    for (int b = 0; b < Bdim; ++b) acc[b] = make_float4(0.f, 0.f, 0.f, 0.f);

    #pragma unroll
    for (int dd = 0; dd < 8; ++dd) {
        int dloc = dd * 8 + wave;            // 0..63, wave-uniform
        const float4 wv = w_pre[dd];
        #pragma unroll
        for (int b = 0; b < Bdim; ++b) {
            float a = A_red[b][dloc];
            acc[b].x += a * wv.x;
            acc[b].y += a * wv.y;
            acc[b].z += a * wv.z;
            acc[b].w += a * wv.w;
        }
    }

    #pragma unroll
    for (int b = 0; b < Bdim; ++b)
        *(float4*)&P[wave][b][c4] = acc[b];
    __syncthreads();

    // ---- final cross-wave reduce -> per-block partial (no global atomics) ----
    {
        int c  = tid & 255;
        int bh = tid >> 8;                   // 0..1 -> handles b = 2*bh, 2*bh+1
        #pragma unroll
        for (int bb = 0; bb < 2; ++bb) {
            int b = bh * 2 + bb;
            float s = 0.0f;
            #pragma unroll
            for (int w2 = 0; w2 < 8; ++w2) s += P[w2][b][c];
            if (USE_WS) {
                // private slice: coalesced stores, zero contention
                dst[(size_t)blockIdx.x * (Bdim * Cdim) + b * Cdim + c] = s;
            } else {
                atomicAdd(&dst[b * Cdim + c], s);   // fallback path only
            }
        }
    }
}

// Reduce 256 per-block partials -> out. Grid 4 x 256: thread (b,c).
// 1 MB of coalesced reads (256 consecutive floats per k-step), no atomics.
__global__ __launch_bounds__(256) void vb_reduce(
    const float* __restrict__ part,      // [NBLK][Bdim*Cdim]
    float*       __restrict__ out)       // [Bdim*Cdim]
{
    const int o = blockIdx.x * 256 + threadIdx.x;   // 0..1023 = b*256+c
    float s = 0.0f;
    #pragma unroll 8
    for (int k = 0; k < NBLK; ++k)
        s += part[(size_t)k * (Bdim * Cdim) + o];
    out[o] = s;
}

extern "C" void kernel_launch(void* const* d_in, const int* in_sizes, int n_in,
                              void* d_out, int out_size, void* d_ws, size_t ws_size,
                              hipStream_t stream) {
    const int*   indices = (const int*)  d_in[0];
    const float* scores  = (const float*)d_in[1];
    const float* W       = (const float*)d_in[2];
    const int*   label   = (const int*)  d_in[3];
    const int*   index_p = (const int*)  d_in[4];
    const float* weight  = (const float*)d_in[5];
    float*       out     = (float*)d_out;

    const size_t need = (size_t)NBLK * Bdim * Cdim * sizeof(float);   // 1 MB
    if (d_ws != nullptr && ws_size >= need) {
        float* part = (float*)d_ws;
        vb_kernel<true><<<dim3(NBLK), dim3(512), 0, stream>>>(
            indices, scores, W, label, index_p, weight, part);
        vb_reduce<<<dim3(4), dim3(256), 0, stream>>>(part, out);
    } else {
        hipMemsetAsync(out, 0, (size_t)out_size * sizeof(float), stream);
        vb_kernel<false><<<dim3(NBLK), dim3(512), 0, stream>>>(
            indices, scores, W, label, index_p, weight, out);
    }
}